// Round 18
// baseline (12.304 us; speedup 1.0000x reference)
//
#include <hip/hip_runtime.h>
#include <math.h>

#define HH 256
#define WW 256
#define NTHREADS 256
#define CHUNKG 1024           // gaussians per staging pass (N fits in one pass)
#define NROUND (CHUNKG / NTHREADS)
#define BPX 64                // pixels (columns) per block
#define CAP 256               // survivor capacity per MFMA batch (batch loop if exceeded)
#define NCHCAP (CAP / 32)
#define HWPIX (HH * WW)
#define ECUT (-9.5f)          // drop gaussians whose BLOCK-peak log2(alpha) < ECUT

typedef short s8v __attribute__((ext_vector_type(8)));   // 8 bf16 (4 VGPRs)
typedef float f4v __attribute__((ext_vector_type(4)));   // MFMA accumulator

__device__ __forceinline__ unsigned pk_trunc(float lo, float hi) {
    return (__float_as_uint(hi) & 0xFFFF0000u) | (__float_as_uint(lo) >> 16);
}
__device__ __forceinline__ short bf16h(float v) {
    return (short)(__float_as_uint(v) >> 16);
}
__device__ __forceinline__ float fexp2(float x) {
    return __builtin_amdgcn_exp2f(x);   // raw v_exp_f32; -inf -> 0
}

// ---------------------------------------------------------------------------
// Single-kernel renderer, quarter-row blocks for occupancy. Block = (row y,
// x-quarter); grid = 1024 -> 4 blocks/CU, 16 waves/CU (LDS ~12.5KB/block).
// All N gaussians staged in one pass: 4 projection rounds in registers ->
// ballot-compact -> survivors processed in CAP=256 batches (1 batch in
// practice; loop guarantees correctness for any distribution):
//   prm3[pos] = {A,B,E} packed 3-float (quadrant = 6 conflict-free b128)
//   payload scattered directly into MFMA B-frag slots via ds_write_b16
//   (bfr zero-filled once; dummy/stale slots finite -> alpha=0 contributes 0)
// Cull: block-range peak coef*((y-v)^2 + dxc^2) + log2(op) > ECUT,
// dxc = clamp(u,x0,x0+BPX-1)-u.  log2(alpha) = A*x^2 + B*x + E.
// GEMM mfma_f32_16x16x32_bf16 (one 16-px tile per wave), k=(lane>>4)*8+j
// both sides; D: col=lane&15 (payload), row=(lane>>4)*4+reg (pixel).
// Epilogue: LDS transpose -> normalize -> 64 px out.
// ---------------------------------------------------------------------------
__global__ __launch_bounds__(NTHREADS) void render_kernel(
    const float* __restrict__ means,
    const float* __restrict__ colors,
    const float* __restrict__ opacity,
    const float* __restrict__ scales,
    const float* __restrict__ K,
    const float* __restrict__ M,
    float* __restrict__ out,
    int N)
{
    __shared__ float    prm3[CAP * 3];            // packed {A,B,E}  (3KB)
    __shared__ unsigned bfr[NCHCAP * 256];        // B-frags         (8KB)
    __shared__ int      scnt[4 * NROUND];
    __shared__ float    esum[5 * BPX];            // epilogue        (1.25KB)

    short* bfr16 = (short*)bfr;

    const int tid  = threadIdx.x;
    const int lane = tid & 63;
    const int wv   = tid >> 6;
    const int y    = blockIdx.x >> 2;
    const int x0   = (blockIdx.x & 3) * BPX;
    const float yf  = (float)y;
    const float x0f = (float)x0;
    const int kq   = (lane >> 4) << 3;   // lane's k-block base (0,8,16,24)

    // one-time zero of all B-frag slots (protected by loop-top barrier)
    for (int e = tid; e < NCHCAP * 256; e += NTHREADS) bfr[e] = 0;

    f4v acc = (f4v){0.f, 0.f, 0.f, 0.f};
    const float xsv  = (float)(x0 + wv * 16 + (lane & 15));
    const float xxsv = xsv * xsv;

    for (int base = 0; base < N; base += CHUNKG) {
        __syncthreads();   // zero-fill done / previous pass fully consumed

        // ---- Phase 1: project NROUND rounds into registers + ballots ----
        float Ar[NROUND], Br[NROUND], Er[NROUND];
        float4 cfr[NROUND];
        bool  keepr[NROUND];
        int   prer[NROUND];

        #pragma unroll
        for (int r = 0; r < NROUND; ++r) {
            const int n = base + r * NTHREADS + tid;
            float A = 0.f, Bc = 0.f, E = -INFINITY;
            float4 cf = make_float4(0.f, 0.f, 0.f, 0.f);
            float blkpeak = -INFINITY;
            if (n < N) {
                const float wx = means[3 * n + 0];
                const float wy = means[3 * n + 1];
                const float wz = means[3 * n + 2];
                const float px = M[0] * wx + M[1] * wy + M[2]  * wz + M[3];
                const float py = M[4] * wx + M[5] * wy + M[6]  * wz + M[7];
                const float pz = M[8] * wx + M[9] * wy + M[10] * wz + M[11];
                const float rz = 1.0f / pz;
                const float u  = (K[0] * px + K[1] * py + K[2] * pz) * rz;
                const float v  = (K[4] * py + K[5] * pz) * rz;
                const bool valid = (pz > 1e-4f)
                                && (u >= -(float)WW) && (u <= 2.0f * (float)WW)
                                && (v >= -(float)HH) && (v <= 2.0f * (float)HH);
                if (valid) {
                    const float op  = opacity[n];
                    const float sig = fmaxf(scales[n] * 256.0f, 1.0f);
                    const float coef = -0.72134752044448170368f / (sig * sig);
                    const float lop = __log2f(op);              // op=0 -> -inf
                    const float dyv = yf - v;
                    const float xc  = fminf(fmaxf(u, x0f), x0f + (float)(BPX - 1));
                    const float dxc = xc - u;
                    blkpeak = fmaf(coef, fmaf(dxc, dxc, dyv * dyv), lop);
                    A  = coef;
                    Bc = -2.0f * coef * u;
                    const float C = -2.0f * coef * v;
                    const float D = fmaf(coef, fmaf(u, u, v * v), lop);
                    E  = fmaf(fmaf(A, yf, C), yf, D);
                    cf = make_float4(colors[3 * n + 0], colors[3 * n + 1],
                                     colors[3 * n + 2], pz);
                }
            }
            const bool keep = (blkpeak > ECUT);
            const unsigned long long mask = __ballot(keep);
            if (lane == 0) scnt[r * 4 + wv] = __popcll(mask);
            Ar[r] = A; Br[r] = Bc; Er[r] = E; cfr[r] = cf;
            keepr[r] = keep;
            prer[r] = __popcll(mask & ((1ull << lane) - 1ull));
        }
        __syncthreads();

        // position bases (round-major, then wave-major)
        int rbase[NROUND];
        int running = 0;
        #pragma unroll
        for (int r = 0; r < NROUND; ++r) {
            int b = running;
            #pragma unroll
            for (int w = 0; w < 4; ++w) {
                if (w < wv) b += scnt[r * 4 + w];
                running += scnt[r * 4 + w];
            }
            rbase[r] = b;
        }
        const int cnt = running;

        // ---- Batched scatter + MFMA (single batch when cnt <= CAP) ----
        for (int s0 = 0; s0 < cnt; s0 += CAP) {
            const int bc   = min(cnt - s0, CAP);
            const int bpad = (bc + 31) & ~31;
            const int nch  = bpad >> 5;

            #pragma unroll
            for (int r = 0; r < NROUND; ++r) {
                if (keepr[r]) {
                    const int pos = rbase[r] + prer[r] - s0;
                    if (pos >= 0 && pos < CAP) {
                        prm3[3 * pos + 0] = Ar[r];
                        prm3[3 * pos + 1] = Br[r];
                        prm3[3 * pos + 2] = Er[r];
                        const int chunk = pos >> 5;
                        const int k     = pos & 31;
                        const int eb    = chunk * 256 + (k >> 3) * 64 + ((k & 7) >> 1);
                        const int par   = k & 1;
                        bfr16[(eb +  0) * 2 + par] = (short)0x3F80;      // col 0: 1.0
                        bfr16[(eb +  4) * 2 + par] = bf16h(cfr[r].x);    // col 1: r
                        bfr16[(eb +  8) * 2 + par] = bf16h(cfr[r].y);    // col 2: g
                        bfr16[(eb + 12) * 2 + par] = bf16h(cfr[r].z);    // col 3: b
                        bfr16[(eb + 16) * 2 + par] = bf16h(cfr[r].w);    // col 4: z
                    }
                }
            }
            if (tid < bpad - bc) {
                const int pos = bc + tid;
                prm3[3 * pos + 0] = 0.f;
                prm3[3 * pos + 1] = 0.f;
                prm3[3 * pos + 2] = -INFINITY;
                // bfr slots for dummies remain finite (0/stale bf16): alpha=0
            }
            __syncthreads();

            // ---- alpha eval + MFMA accumulate over this batch ----
            __builtin_amdgcn_s_setprio(1);
            const float4* prm4 = (const float4*)prm3;
            #pragma unroll 2
            for (int c = 0; c < nch; ++c) {
                const int qb = 24 * c + 6 * (kq >> 3);
                float4 q0 = prm4[qb + 0], q1 = prm4[qb + 1], q2 = prm4[qb + 2];
                float4 q3 = prm4[qb + 3], q4 = prm4[qb + 4], q5 = prm4[qb + 5];
                const float Ag[8] = {q0.x, q0.w, q1.z, q2.y, q3.x, q3.w, q4.z, q5.y};
                const float Bg[8] = {q0.y, q1.x, q1.w, q2.z, q3.y, q4.x, q4.w, q5.z};
                const float Eg[8] = {q0.z, q1.y, q2.x, q2.w, q3.z, q4.y, q5.x, q5.w};

                union { s8v v; uint4 q; } Bf;
                Bf.q = *(const uint4*)&bfr[c * 256 + lane * 4];

                union { s8v v; unsigned u[4]; } Af;
                #pragma unroll
                for (int r = 0; r < 4; ++r) {
                    const float a0 = fminf(fexp2(fmaf(Bg[2*r],   xsv, fmaf(Ag[2*r],   xxsv, Eg[2*r]))),   0.95f);
                    const float a1 = fminf(fexp2(fmaf(Bg[2*r+1], xsv, fmaf(Ag[2*r+1], xxsv, Eg[2*r+1]))), 0.95f);
                    Af.u[r] = pk_trunc(a0, a1);
                }
                acc = __builtin_amdgcn_mfma_f32_16x16x32_bf16(Af.v, Bf.v, acc, 0, 0, 0);
            }
            __builtin_amdgcn_s_setprio(0);
            __syncthreads();   // batch consumed before next batch overwrites
        }
    }

    // ---- Epilogue: transpose acc through LDS, normalize, store ----
    __syncthreads();
    const int col = lane & 15;
    if (col < 5) {
        const int rb = (lane >> 4) << 2;
        #pragma unroll
        for (int r = 0; r < 4; ++r) {
            esum[col * BPX + wv * 16 + rb + r] = acc[r];
        }
    }
    __syncthreads();

    if (tid < BPX) {
        const float s  = esum[0 * BPX + tid];
        const float ar = esum[1 * BPX + tid];
        const float ag = esum[2 * BPX + tid];
        const float ab = esum[3 * BPX + tid];
        const float az = esum[4 * BPX + tid];
        const float inv   = 1.0f / (s + 1e-6f);
        const float accum = fminf(s, 1.0f);
        const float bg    = 1.0f - accum;
        float* o = out + (size_t)y * WW + x0 + tid;
        o[0 * HWPIX] = fminf(fmaxf(fmaf(ar * inv, accum, bg), 0.0f), 1.0f);
        o[1 * HWPIX] = fminf(fmaxf(fmaf(ag * inv, accum, bg), 0.0f), 1.0f);
        o[2 * HWPIX] = fminf(fmaxf(fmaf(ab * inv, accum, bg), 0.0f), 1.0f);
        o[3 * HWPIX] = accum;
        o[4 * HWPIX] = az * inv;
    }
}

extern "C" void kernel_launch(void* const* d_in, const int* in_sizes, int n_in,
                              void* d_out, int out_size, void* d_ws, size_t ws_size,
                              hipStream_t stream) {
    const float* means      = (const float*)d_in[0];
    const float* colors     = (const float*)d_in[1];
    const float* opacity    = (const float*)d_in[2];
    const float* scales     = (const float*)d_in[3];
    const float* intrinsics = (const float*)d_in[4];
    const float* w2c        = (const float*)d_in[5];
    float* out = (float*)d_out;

    const int N = in_sizes[0] / 3;

    render_kernel<<<HH * 4, NTHREADS, 0, stream>>>(
        means, colors, opacity, scales, intrinsics, w2c, out, N);
}

// Round 19
// 11.900 us; speedup vs baseline: 1.0339x; 1.0339x over previous
//
#include <hip/hip_runtime.h>
#include <math.h>

#define HH 256
#define WW 256
#define NTHREADS 256
#define CHUNKG 1024           // gaussians per staging pass (N fits in one pass)
#define NROUND (CHUNKG / NTHREADS)
#define BPX 128               // pixels (columns) per block
#define HWPIX (HH * WW)
#define ECUT (-9.5f)          // drop gaussians whose BLOCK-peak log2(alpha) < ECUT

typedef short s8v __attribute__((ext_vector_type(8)));   // 8 bf16 (4 VGPRs)
typedef float f4v __attribute__((ext_vector_type(4)));   // MFMA accumulator

__device__ __forceinline__ unsigned pk_trunc(float lo, float hi) {
    return (__float_as_uint(hi) & 0xFFFF0000u) | (__float_as_uint(lo) >> 16);
}
__device__ __forceinline__ short bf16h(float v) {
    return (short)(__float_as_uint(v) >> 16);
}
__device__ __forceinline__ float fexp2(float x) {
    return __builtin_amdgcn_exp2f(x);   // raw v_exp_f32; -inf -> 0
}

// ---------------------------------------------------------------------------
// Single-kernel, single-pass renderer (R17 base, 12.09us). Block = (row y,
// x-half); grid = 512. R19 deltas:
//  (1) T14 issue-early: ALL 32 projection loads issued into registers before
//      any projection compute (no per-round load->use serialization).
//  (2) Minimal barrier schedule: B1 (scnt+zerofill) -> scatter -> B2 ->
//      MFMA -> B3 (pass end; protects LDS for next pass) -> epilogue B4.
// Cull: block-range peak coef*((y-v)^2 + dxc^2) + log2(op) > ECUT,
// dxc = clamp(u,x0,x0+BPX-1)-u.  log2(alpha) = A*x^2 + B*x + E.
// prm3 packed {A,B,E} (quadrant = 6 conflict-free b128); payload scattered
// directly into MFMA B-frag slots via ds_write_b16 (bfr zero-filled once;
// dummy/stale slots finite -> alpha=0 contributes exact 0).
// GEMM mfma_f32_16x16x32_bf16, k=(lane>>4)*8+j both sides;
// D: col=lane&15, row=(lane>>4)*4+reg. Epilogue: LDS transpose -> out.
// ---------------------------------------------------------------------------
__global__ __launch_bounds__(NTHREADS) void render_kernel(
    const float* __restrict__ means,
    const float* __restrict__ colors,
    const float* __restrict__ opacity,
    const float* __restrict__ scales,
    const float* __restrict__ K,
    const float* __restrict__ M,
    float* __restrict__ out,
    int N)
{
    __shared__ float    prm3[CHUNKG * 3];              // packed {A,B,E} (12KB)
    __shared__ unsigned bfr[(CHUNKG / 32) * 256];      // B-frags (32KB)
    __shared__ int      scnt[4 * NROUND];
    __shared__ float    esum[5 * BPX];

    short* bfr16 = (short*)bfr;

    const int tid  = threadIdx.x;
    const int lane = tid & 63;
    const int wv   = tid >> 6;
    const int y    = blockIdx.x >> 1;
    const int x0   = (blockIdx.x & 1) * BPX;
    const float yf  = (float)y;
    const float x0f = (float)x0;
    const int kq   = (lane >> 4) << 3;   // lane's k-block base (0,8,16,24)

    // one-time zero of all B-frag slots (visible after B1)
    for (int e = tid; e < (CHUNKG / 32) * 256; e += NTHREADS) bfr[e] = 0;

    f4v acc[2];
    acc[0] = (f4v){0.f, 0.f, 0.f, 0.f};
    acc[1] = (f4v){0.f, 0.f, 0.f, 0.f};

    float xs[2], xxs[2];
    #pragma unroll
    for (int t = 0; t < 2; ++t) {
        xs[t]  = (float)(x0 + wv * 32 + t * 16 + (lane & 15));
        xxs[t] = xs[t] * xs[t];
    }

    for (int base = 0; base < N; base += CHUNKG) {
        // ---- Phase 1a: issue ALL projection loads first (T14) ----
        float rw[NROUND][8];
        #pragma unroll
        for (int r = 0; r < NROUND; ++r) {
            const int n  = base + r * NTHREADS + tid;
            const int nc = min(n, N - 1);
            rw[r][0] = means[3 * nc + 0];
            rw[r][1] = means[3 * nc + 1];
            rw[r][2] = means[3 * nc + 2];
            rw[r][3] = colors[3 * nc + 0];
            rw[r][4] = colors[3 * nc + 1];
            rw[r][5] = colors[3 * nc + 2];
            rw[r][6] = opacity[nc];
            rw[r][7] = scales[nc];
        }

        // ---- Phase 1b: projection compute (ILP-4 over rounds) ----
        float Ar[NROUND], Br[NROUND], Er[NROUND];
        float4 cfr[NROUND];
        bool  keepr[NROUND];
        int   prer[NROUND];

        #pragma unroll
        for (int r = 0; r < NROUND; ++r) {
            const int n = base + r * NTHREADS + tid;
            float A = 0.f, Bc = 0.f, E = -INFINITY;
            float4 cf = make_float4(0.f, 0.f, 0.f, 0.f);
            float blkpeak = -INFINITY;
            if (n < N) {
                const float wx = rw[r][0], wy = rw[r][1], wz = rw[r][2];
                const float px = M[0] * wx + M[1] * wy + M[2]  * wz + M[3];
                const float py = M[4] * wx + M[5] * wy + M[6]  * wz + M[7];
                const float pz = M[8] * wx + M[9] * wy + M[10] * wz + M[11];
                const float rz = 1.0f / pz;
                const float u  = (K[0] * px + K[1] * py + K[2] * pz) * rz;
                const float v  = (K[4] * py + K[5] * pz) * rz;
                const bool valid = (pz > 1e-4f)
                                && (u >= -(float)WW) && (u <= 2.0f * (float)WW)
                                && (v >= -(float)HH) && (v <= 2.0f * (float)HH);
                if (valid) {
                    const float op  = rw[r][6];
                    const float sig = fmaxf(rw[r][7] * 256.0f, 1.0f);
                    const float coef = -0.72134752044448170368f / (sig * sig);
                    const float lop = __log2f(op);              // op=0 -> -inf
                    const float dyv = yf - v;
                    const float xc  = fminf(fmaxf(u, x0f), x0f + (float)(BPX - 1));
                    const float dxc = xc - u;
                    blkpeak = fmaf(coef, fmaf(dxc, dxc, dyv * dyv), lop);
                    A  = coef;
                    Bc = -2.0f * coef * u;
                    const float C = -2.0f * coef * v;
                    const float D = fmaf(coef, fmaf(u, u, v * v), lop);
                    E  = fmaf(fmaf(A, yf, C), yf, D);
                    cf = make_float4(rw[r][3], rw[r][4], rw[r][5], pz);
                }
            }
            const bool keep = (blkpeak > ECUT);
            const unsigned long long mask = __ballot(keep);
            if (lane == 0) scnt[r * 4 + wv] = __popcll(mask);
            Ar[r] = A; Br[r] = Bc; Er[r] = E; cfr[r] = cf;
            keepr[r] = keep;
            prer[r] = __popcll(mask & ((1ull << lane) - 1ull));
        }
        __syncthreads();   // B1: scnt visible (+ zero-fill on first pass)

        // position bases (round-major, then wave-major)
        int rbase[NROUND];
        int running = 0;
        #pragma unroll
        for (int r = 0; r < NROUND; ++r) {
            int b = running;
            #pragma unroll
            for (int w = 0; w < 4; ++w) {
                if (w < wv) b += scnt[r * 4 + w];
                running += scnt[r * 4 + w];
            }
            rbase[r] = b;
        }
        const int cnt    = running;
        const int padded = (cnt + 31) & ~31;
        const int nch    = padded >> 5;

        // ---- Phase 2: compacted scatter (prm3 + direct B-frag b16) ----
        #pragma unroll
        for (int r = 0; r < NROUND; ++r) {
            if (keepr[r]) {
                const int pos = rbase[r] + prer[r];
                prm3[3 * pos + 0] = Ar[r];
                prm3[3 * pos + 1] = Br[r];
                prm3[3 * pos + 2] = Er[r];
                const int chunk = pos >> 5;
                const int k     = pos & 31;
                const int eb    = chunk * 256 + (k >> 3) * 64 + ((k & 7) >> 1);
                const int par   = k & 1;
                bfr16[(eb +  0) * 2 + par] = (short)0x3F80;      // col 0: 1.0
                bfr16[(eb +  4) * 2 + par] = bf16h(cfr[r].x);    // col 1: r
                bfr16[(eb +  8) * 2 + par] = bf16h(cfr[r].y);    // col 2: g
                bfr16[(eb + 12) * 2 + par] = bf16h(cfr[r].z);    // col 3: b
                bfr16[(eb + 16) * 2 + par] = bf16h(cfr[r].w);    // col 4: z
            }
        }
        if (tid < padded - cnt) {
            const int pos = cnt + tid;
            prm3[3 * pos + 0] = 0.f;
            prm3[3 * pos + 1] = 0.f;
            prm3[3 * pos + 2] = -INFINITY;
            // bfr slots for dummies remain finite (0 or stale bf16): alpha=0
        }
        __syncthreads();   // B2: staged data visible

        // ---- Phase 3: alpha eval + MFMA accumulate ----
        __builtin_amdgcn_s_setprio(1);
        const float4* prm4 = (const float4*)prm3;
        #pragma unroll 2
        for (int c = 0; c < nch; ++c) {
            const int qb = 24 * c + 6 * (kq >> 3);
            float4 q0 = prm4[qb + 0], q1 = prm4[qb + 1], q2 = prm4[qb + 2];
            float4 q3 = prm4[qb + 3], q4 = prm4[qb + 4], q5 = prm4[qb + 5];
            const float Ag[8] = {q0.x, q0.w, q1.z, q2.y, q3.x, q3.w, q4.z, q5.y};
            const float Bg[8] = {q0.y, q1.x, q1.w, q2.z, q3.y, q4.x, q4.w, q5.z};
            const float Eg[8] = {q0.z, q1.y, q2.x, q2.w, q3.z, q4.y, q5.x, q5.w};

            union { s8v v; uint4 q; } Bf;
            Bf.q = *(const uint4*)&bfr[c * 256 + lane * 4];

            #pragma unroll
            for (int t = 0; t < 2; ++t) {
                union { s8v v; unsigned u[4]; } Af;
                #pragma unroll
                for (int r = 0; r < 4; ++r) {
                    const float a0 = fminf(fexp2(fmaf(Bg[2*r],   xs[t], fmaf(Ag[2*r],   xxs[t], Eg[2*r]))),   0.95f);
                    const float a1 = fminf(fexp2(fmaf(Bg[2*r+1], xs[t], fmaf(Ag[2*r+1], xxs[t], Eg[2*r+1]))), 0.95f);
                    Af.u[r] = pk_trunc(a0, a1);
                }
                acc[t] = __builtin_amdgcn_mfma_f32_16x16x32_bf16(Af.v, Bf.v, acc[t], 0, 0, 0);
            }
        }
        __builtin_amdgcn_s_setprio(0);
        __syncthreads();   // B3: pass consumed (protects LDS reuse / epilogue)
    }

    // ---- Epilogue: transpose acc through LDS, normalize, store ----
    const int col = lane & 15;
    if (col < 5) {
        const int rb = (lane >> 4) << 2;
        #pragma unroll
        for (int t = 0; t < 2; ++t) {
            #pragma unroll
            for (int r = 0; r < 4; ++r) {
                esum[col * BPX + wv * 32 + t * 16 + rb + r] = acc[t][r];
            }
        }
    }
    __syncthreads();       // B4

    if (tid < BPX) {
        const float s  = esum[0 * BPX + tid];
        const float ar = esum[1 * BPX + tid];
        const float ag = esum[2 * BPX + tid];
        const float ab = esum[3 * BPX + tid];
        const float az = esum[4 * BPX + tid];
        const float inv   = 1.0f / (s + 1e-6f);
        const float accum = fminf(s, 1.0f);
        const float bg    = 1.0f - accum;
        float* o = out + (size_t)y * WW + x0 + tid;
        o[0 * HWPIX] = fminf(fmaxf(fmaf(ar * inv, accum, bg), 0.0f), 1.0f);
        o[1 * HWPIX] = fminf(fmaxf(fmaf(ag * inv, accum, bg), 0.0f), 1.0f);
        o[2 * HWPIX] = fminf(fmaxf(fmaf(ab * inv, accum, bg), 0.0f), 1.0f);
        o[3 * HWPIX] = accum;
        o[4 * HWPIX] = az * inv;
    }
}

extern "C" void kernel_launch(void* const* d_in, const int* in_sizes, int n_in,
                              void* d_out, int out_size, void* d_ws, size_t ws_size,
                              hipStream_t stream) {
    const float* means      = (const float*)d_in[0];
    const float* colors     = (const float*)d_in[1];
    const float* opacity    = (const float*)d_in[2];
    const float* scales     = (const float*)d_in[3];
    const float* intrinsics = (const float*)d_in[4];
    const float* w2c        = (const float*)d_in[5];
    float* out = (float*)d_out;

    const int N = in_sizes[0] / 3;

    render_kernel<<<HH * 2, NTHREADS, 0, stream>>>(
        means, colors, opacity, scales, intrinsics, w2c, out, N);
}